// Round 1
// baseline (2142.820 us; speedup 1.0000x reference)
//
#include <hip/hip_runtime.h>
#include <math.h>

// Problem constants (B, C, H, W) = (4, 128, 192, 192)
#define BB 4
#define CC 128
#define HH 192
#define WW 192
#define HWSZ (HH * WW)          // 36864
#define NPIX (BB * HWSZ)        // 147456

// ---------------------------------------------------------------------------
// Weight pre-transpose:  w[co][cin][ky][kx]  ->  wT[cin*9+tap][co]
// Makes conv-kernel weight staging fully coalesced (global) and sequential
// (LDS writes, conflict-free).
// ---------------------------------------------------------------------------
__global__ void transpose_w_kernel(const float* __restrict__ w,
                                   float* __restrict__ wT,
                                   int CIN, int COUT, int total) {
    int idx = blockIdx.x * blockDim.x + threadIdx.x;
    if (idx >= total) return;
    int co  = idx % COUT;
    int rem = idx / COUT;
    int tap = rem % 9;
    int cin = rem / 9;
    wT[idx] = w[(co * CIN + cin) * 9 + tap];
}

// ---------------------------------------------------------------------------
// Direct 3x3 conv, pad=1, fp32, register-blocked 8 couts x 8 pixels / thread.
// Tile: 8 rows x 32 cols of output, COUT_TILE output channels per block.
// Threads = (COUT_TILE/8) * 32.
// ---------------------------------------------------------------------------
template <int CIN, int COUT, int COUT_TILE, bool RELU>
__global__ __launch_bounds__((COUT_TILE / 8) * 32)
void conv3x3_kernel(const float* __restrict__ in,
                    const float* __restrict__ wT,   // [cin*9+tap][COUT]
                    const float* __restrict__ bias,
                    float* __restrict__ out) {
    constexpr int PH = 8, PW = 32, CK = 8;
    constexpr int CO_T = 8, P_T = 8;
    constexpr int CO_GROUPS = COUT_TILE / CO_T;
    constexpr int NT = CO_GROUPS * 32;
    constexpr int CO_TILES = COUT / COUT_TILE;

    __shared__ __align__(16) float s_in[CK][PH + 2][PW + 4]; // stride 36 -> 16B-aligned rows
    __shared__ __align__(16) float s_w[CK][9][COUT_TILE];

    const int tid = threadIdx.x;
    const int tw  = blockIdx.x;              // 0..5
    const int th  = blockIdx.y;              // 0..23
    const int bz  = blockIdx.z;
    const int b   = bz / CO_TILES;
    const int ct  = bz % CO_TILES;

    const int cg = tid / 32;                 // cout group
    const int pg = tid % 32;                 // pixel group
    const int r  = pg >> 2;                  // row in tile 0..7
    const int cb = (pg & 3) * 8;             // col base 0,8,16,24

    float acc[CO_T][P_T];
#pragma unroll
    for (int i = 0; i < CO_T; ++i)
#pragma unroll
        for (int j = 0; j < P_T; ++j) acc[i][j] = 0.f;

    const int gh0 = th * PH - 1;
    const int gw0 = tw * PW - 1;

    for (int chunk = 0; chunk < CIN / CK; ++chunk) {
        // --- stage input tile (with halo, zero-padded) ---
        for (int i = tid; i < CK * (PH + 2) * (PW + 2); i += NT) {
            int col = i % (PW + 2);
            int rem = i / (PW + 2);
            int row = rem % (PH + 2);
            int k   = rem / (PH + 2);
            int gh = gh0 + row, gw = gw0 + col;
            float v = 0.f;
            if ((unsigned)gh < (unsigned)HH && (unsigned)gw < (unsigned)WW)
                v = in[((b * CIN + chunk * CK + k) * HH + gh) * WW + gw];
            s_in[k][row][col] = v;
        }
        // --- stage weight chunk: contiguous copy, coalesced + conflict-free ---
        {
            const float* src = wT + (size_t)(chunk * CK * 9) * COUT + ct * COUT_TILE;
            float* dst = &s_w[0][0][0];
            for (int i = tid; i < CK * 9 * COUT_TILE; i += NT) {
                int co = i % COUT_TILE;
                int kt = i / COUT_TILE;
                dst[i] = src[(size_t)kt * COUT + co];
            }
        }
        __syncthreads();

#pragma unroll
        for (int k = 0; k < CK; ++k) {
#pragma unroll
            for (int dy = 0; dy < 3; ++dy) {
                const float4 r0 = *(const float4*)&s_in[k][r + dy][cb];
                const float4 r1 = *(const float4*)&s_in[k][r + dy][cb + 4];
                const float4 r2 = *(const float4*)&s_in[k][r + dy][cb + 8];
                float rowv[12] = {r0.x, r0.y, r0.z, r0.w, r1.x, r1.y,
                                  r1.z, r1.w, r2.x, r2.y, r2.z, r2.w};
#pragma unroll
                for (int dx = 0; dx < 3; ++dx) {
                    const float4 w0 = *(const float4*)&s_w[k][dy * 3 + dx][cg * CO_T];
                    const float4 w1 = *(const float4*)&s_w[k][dy * 3 + dx][cg * CO_T + 4];
                    float wv[8] = {w0.x, w0.y, w0.z, w0.w, w1.x, w1.y, w1.z, w1.w};
#pragma unroll
                    for (int co = 0; co < CO_T; ++co)
#pragma unroll
                        for (int p = 0; p < P_T; ++p)
                            acc[co][p] = fmaf(wv[co], rowv[p + dx], acc[co][p]);
                }
            }
        }
        __syncthreads();
    }

    // --- epilogue: bias (+ReLU) and vectorized store ---
    const int gh = th * PH + r;
    const int gw = tw * PW + cb;
#pragma unroll
    for (int co = 0; co < CO_T; ++co) {
        int cog = ct * COUT_TILE + cg * CO_T + co;
        float bv = bias[cog];
        float tmp[8];
#pragma unroll
        for (int p = 0; p < P_T; ++p) {
            float v = acc[co][p] + bv;
            if (RELU) v = fmaxf(v, 0.f);
            tmp[p] = v;
        }
        float* op = out + ((size_t)(b * COUT + cog) * HH + gh) * WW + gw;
        *(float4*)op       = make_float4(tmp[0], tmp[1], tmp[2], tmp[3]);
        *(float4*)(op + 4) = make_float4(tmp[4], tmp[5], tmp[6], tmp[7]);
    }
}

// ---------------------------------------------------------------------------
// conv1x1 (32 -> 9 logits) + softmax over the 9 taps
// ---------------------------------------------------------------------------
__global__ void conv1x1_softmax_kernel(const float* __restrict__ in,   // (B,32,H,W)
                                       const float* __restrict__ w3,   // (9,32)
                                       const float* __restrict__ b3,   // (9,)
                                       float* __restrict__ kern) {     // (B,9,H,W)
    __shared__ float sw[9 * 32];
    __shared__ float sb[9];
    for (int i = threadIdx.x; i < 9 * 32; i += blockDim.x) sw[i] = w3[i];
    if (threadIdx.x < 9) sb[threadIdx.x] = b3[threadIdx.x];
    __syncthreads();

    int idx = blockIdx.x * blockDim.x + threadIdx.x;
    if (idx >= NPIX) return;
    int b = idx / HWSZ;
    int p = idx % HWSZ;

    float v[32];
#pragma unroll
    for (int c = 0; c < 32; ++c) v[c] = in[((size_t)(b * 32 + c)) * HWSZ + p];

    float lg[9];
    float m = -1e30f;
#pragma unroll
    for (int t = 0; t < 9; ++t) {
        float s = sb[t];
#pragma unroll
        for (int c = 0; c < 32; ++c) s = fmaf(sw[t * 32 + c], v[c], s);
        lg[t] = s;
        m = fmaxf(m, s);
    }
    float sum = 0.f;
#pragma unroll
    for (int t = 0; t < 9; ++t) {
        lg[t] = __expf(lg[t] - m);
        sum += lg[t];
    }
    float inv = 1.f / sum;
#pragma unroll
    for (int t = 0; t < 9; ++t)
        kern[((size_t)(b * 9 + t)) * HWSZ + p] = lg[t] * inv;
}

// ---------------------------------------------------------------------------
// Adaptive 3x3 filter apply: out[b,c,h,w] = sum_t kern[b,t,h,w] * xpad[...]
// ---------------------------------------------------------------------------
__global__ void deblur_kernel(const float* __restrict__ x,
                              const float* __restrict__ kern,
                              float* __restrict__ out) {
    int idx = blockIdx.x * blockDim.x + threadIdx.x;
    if (idx >= BB * CC * HWSZ) return;
    int w_ = idx % WW;
    int h  = (idx / WW) % HH;
    int c  = (idx / HWSZ) % CC;
    int b  = idx / (HWSZ * CC);

    const float* kb = kern + (size_t)(b * 9) * HWSZ + h * WW + w_;
    const float* xb = x + (size_t)(b * CC + c) * HWSZ;
    float sum = 0.f;
    int t = 0;
#pragma unroll
    for (int dy = 0; dy < 3; ++dy) {
#pragma unroll
        for (int dx = 0; dx < 3; ++dx) {
            int hh = h + dy - 1, ww2 = w_ + dx - 1;
            float xv = ((unsigned)hh < (unsigned)HH && (unsigned)ww2 < (unsigned)WW)
                           ? xb[hh * WW + ww2] : 0.f;
            sum = fmaf(kb[(size_t)t * HWSZ], xv, sum);
            ++t;
        }
    }
    out[idx] = sum;
}

// ---------------------------------------------------------------------------
extern "C" void kernel_launch(void* const* d_in, const int* in_sizes, int n_in,
                              void* d_out, int out_size, void* d_ws, size_t ws_size,
                              hipStream_t stream) {
    const float* x   = (const float*)d_in[0];
    const float* w1  = (const float*)d_in[1];
    const float* b1  = (const float*)d_in[2];
    const float* w2  = (const float*)d_in[3];
    const float* b2  = (const float*)d_in[4];
    const float* w3  = (const float*)d_in[5];
    const float* b3  = (const float*)d_in[6];
    const float* f1  = (const float*)d_in[7];
    const float* fb1 = (const float*)d_in[8];
    const float* f2  = (const float*)d_in[9];
    const float* fb2 = (const float*)d_in[10];
    float* out = (float*)d_out;

    // workspace layout (floats)
    float* ws = (float*)d_ws;
    const size_t SZ_FULL = (size_t)BB * CC * HWSZ;        // 18,874,368
    float* regionA = ws;                                  // t1 then t3
    float* regionB = regionA + SZ_FULL;                   // t2 then t4
    float* kern    = regionB + SZ_FULL;                   // (B,9,H,W)
    float* w1T     = kern + (size_t)BB * 9 * HWSZ;
    float* w2T     = w1T + 64 * 128 * 9;
    float* f1T     = w2T + 32 * 64 * 9;
    float* f2T     = f1T + 128 * 128 * 9;

    float* t1 = regionA;   // (B,64,H,W)
    float* t2 = regionB;   // (B,32,H,W)
    float* t3 = regionA;   // (B,128,H,W)  overwrites t1 (dead)
    float* t4 = regionB;   // (B,128,H,W)  overwrites t2 (dead)

    // weight transposes
    {
        int n1 = 64 * 128 * 9, n2 = 32 * 64 * 9, nf = 128 * 128 * 9;
        transpose_w_kernel<<<(n1 + 255) / 256, 256, 0, stream>>>(w1, w1T, 128, 64, n1);
        transpose_w_kernel<<<(n2 + 255) / 256, 256, 0, stream>>>(w2, w2T, 64, 32, n2);
        transpose_w_kernel<<<(nf + 255) / 256, 256, 0, stream>>>(f1, f1T, 128, 128, nf);
        transpose_w_kernel<<<(nf + 255) / 256, 256, 0, stream>>>(f2, f2T, 128, 128, nf);
    }

    // conv1: 128 -> 64, relu
    conv3x3_kernel<128, 64, 64, true>
        <<<dim3(6, 24, 4), 256, 0, stream>>>(x, w1T, b1, t1);
    // conv2: 64 -> 32, relu
    conv3x3_kernel<64, 32, 32, true>
        <<<dim3(6, 24, 4), 128, 0, stream>>>(t1, w2T, b2, t2);
    // conv3 1x1 + softmax -> kern
    conv1x1_softmax_kernel<<<(NPIX + 255) / 256, 256, 0, stream>>>(t2, w3, b3, kern);
    // adaptive filter apply
    deblur_kernel<<<((int)((size_t)BB * CC * HWSZ) + 255) / 256, 256, 0, stream>>>(x, kern, t3);
    // f1: 128 -> 128, relu
    conv3x3_kernel<128, 128, 64, true>
        <<<dim3(6, 24, 8), 256, 0, stream>>>(t3, f1T, fb1, t4);
    // f2: 128 -> 128, no relu -> final output
    conv3x3_kernel<128, 128, 64, false>
        <<<dim3(6, 24, 8), 256, 0, stream>>>(t4, f2T, fb2, out);
}

// Round 2
// 468.029 us; speedup vs baseline: 4.5784x; 4.5784x over previous
//
#include <hip/hip_runtime.h>
#include <math.h>

// Problem constants (B, C, H, W) = (4, 128, 192, 192)
#define BB 4
#define CC 128
#define HH 192
#define WW 192
#define HWSZ (HH * WW)          // 36864
#define NPIX (BB * HWSZ)        // 147456

typedef __attribute__((ext_vector_type(8))) short short8;
typedef __attribute__((ext_vector_type(4))) float float4v;

// fp32 -> bf16, round-to-nearest-even
__device__ __forceinline__ short f2bf(float f) {
    unsigned u = __float_as_uint(f);
    u += 0x7FFF + ((u >> 16) & 1);
    return (short)(u >> 16);
}

// ---------------------------------------------------------------------------
// Weight prep:  w[co][cin][ky][kx] fp32  ->  wp[tap][ck][co][ci] bf16
// (tap = ky*3+kx, cin = ck*32+ci).  A-frag loads become contiguous 16B/lane.
// ---------------------------------------------------------------------------
__global__ void prep_w_kernel(const float* __restrict__ w,
                              short* __restrict__ wp,
                              int CIN, int COUT, int total) {
    int idx = blockIdx.x * blockDim.x + threadIdx.x;
    if (idx >= total) return;
    int ci  = idx & 31;
    int co  = (idx >> 5) % COUT;
    int rem = (idx >> 5) / COUT;
    int CKN = CIN / 32;
    int ck  = rem % CKN;
    int tap = rem / CKN;
    int cin = ck * 32 + ci;
    wp[idx] = f2bf(w[(co * CIN + cin) * 9 + tap]);
}

// ---------------------------------------------------------------------------
// Implicit-GEMM 3x3 conv, pad=1, bf16 MFMA (16x16x32), fp32 accumulate.
// Block: one (b, h) row -> N = 192 pixels x COUT couts.
// K order = (tap, cin): per tap, K=32 chunks are 32 consecutive cins.
// LDS: input slab only, [3 rows][4 cin-groups][194 padded cols][8 cins] bf16.
// Weights read directly from global (L2-resident, coalesced 16B/lane).
// ---------------------------------------------------------------------------
template <int CIN, int COUT, int WAVES_M, int WAVES_N, int WM, int WN, bool RELU>
__global__ __launch_bounds__(WAVES_M * WAVES_N * 64)
void conv3x3_mfma(const float* __restrict__ in,
                  const short* __restrict__ wp,
                  const float* __restrict__ bias,
                  float* __restrict__ out) {
    constexpr int CKN = CIN / 32;
    constexpr int NT  = WAVES_M * WAVES_N * 64;
    static_assert(WAVES_M * WM * 16 == COUT, "M tiling");
    static_assert(WAVES_N * WN * 16 == 192, "N tiling");

    __shared__ short s_x[3 * 4 * 194 * 8];   // 37,248 B

    const int tid  = threadIdx.x;
    const int h    = blockIdx.x;
    const int b    = blockIdx.y;
    const int lane = tid & 63;
    const int wv   = tid >> 6;
    const int wv_m = wv % WAVES_M;
    const int wv_n = wv / WAVES_M;
    const int ln15 = lane & 15;
    const int lg   = lane >> 4;              // k-group 0..3

    float4v acc[WM][WN];
#pragma unroll
    for (int mi = 0; mi < WM; ++mi)
#pragma unroll
        for (int ni = 0; ni < WN; ++ni)
            acc[mi][ni] = (float4v){0.f, 0.f, 0.f, 0.f};

    const float* inb = in + (size_t)b * CIN * HWSZ;

    for (int ck = 0; ck < CKN; ++ck) {
        // ---- stage input slab: 3 rows x 4 groups x 194 cols, bf16-packed ----
        for (int i = tid; i < 3 * 4 * 194; i += NT) {
            int col = i % 194;
            int rem = i / 194;
            int g   = rem & 3;
            int row = rem >> 2;
            int hh  = h + row - 1;
            int wn  = col - 1;
            short8 pk;
            if ((unsigned)hh < (unsigned)HH && (unsigned)wn < (unsigned)WW) {
                const float* p = inb + ((size_t)(ck * 32 + g * 8) * HH + hh) * WW + wn;
#pragma unroll
                for (int j = 0; j < 8; ++j) pk[j] = f2bf(p[(size_t)j * HWSZ]);
            } else {
#pragma unroll
                for (int j = 0; j < 8; ++j) pk[j] = 0;
            }
            *(short8*)&s_x[i * 8] = pk;      // ds_write_b128, conflict-free
        }
        __syncthreads();

        // ---- 9 taps x (A global loads + B LDS b128 + MFMA) ----
#pragma unroll
        for (int tap = 0; tap < 9; ++tap) {
            const int dy = tap / 3, dx = tap % 3;
            short8 a[WM];
#pragma unroll
            for (int mi = 0; mi < WM; ++mi) {
                int co = (wv_m * WM + mi) * 16 + ln15;
                a[mi] = *(const short8*)&wp[(((size_t)tap * CKN + ck) * COUT + co) * 32 + lg * 8];
            }
            short8 bf[WN];
#pragma unroll
            for (int ni = 0; ni < WN; ++ni) {
                int col  = (wv_n * WN + ni) * 16 + ln15 + dx;   // padded col
                int unit = (dy * 4 + lg) * 194 + col;
                bf[ni] = *(const short8*)&s_x[unit * 8];        // ds_read_b128
            }
#pragma unroll
            for (int mi = 0; mi < WM; ++mi)
#pragma unroll
                for (int ni = 0; ni < WN; ++ni)
                    acc[mi][ni] = __builtin_amdgcn_mfma_f32_16x16x32_bf16(
                        a[mi], bf[ni], acc[mi][ni], 0, 0, 0);
        }
        __syncthreads();
    }

    // ---- epilogue: C layout col=lane&15 (pixel), row=(lane>>4)*4+reg (cout) ----
#pragma unroll
    for (int mi = 0; mi < WM; ++mi) {
        int co0 = (wv_m * WM + mi) * 16 + lg * 4;
#pragma unroll
        for (int r = 0; r < 4; ++r) {
            int co = co0 + r;
            float bv = bias[co];
#pragma unroll
            for (int ni = 0; ni < WN; ++ni) {
                int wcol = (wv_n * WN + ni) * 16 + ln15;
                float v = acc[mi][ni][r] + bv;
                if (RELU) v = fmaxf(v, 0.f);
                out[((size_t)(b * COUT + co) * HH + h) * WW + wcol] = v;
            }
        }
    }
}

// ---------------------------------------------------------------------------
// conv1x1 (32 -> 9 logits) + softmax over the 9 taps (fp32, exact)
// ---------------------------------------------------------------------------
__global__ void conv1x1_softmax_kernel(const float* __restrict__ in,   // (B,32,H,W)
                                       const float* __restrict__ w3,   // (9,32)
                                       const float* __restrict__ b3,   // (9,)
                                       float* __restrict__ kern) {     // (B,9,H,W)
    __shared__ float sw[9 * 32];
    __shared__ float sb[9];
    for (int i = threadIdx.x; i < 9 * 32; i += blockDim.x) sw[i] = w3[i];
    if (threadIdx.x < 9) sb[threadIdx.x] = b3[threadIdx.x];
    __syncthreads();

    int idx = blockIdx.x * blockDim.x + threadIdx.x;
    if (idx >= NPIX) return;
    int b = idx / HWSZ;
    int p = idx % HWSZ;

    float v[32];
#pragma unroll
    for (int c = 0; c < 32; ++c) v[c] = in[((size_t)(b * 32 + c)) * HWSZ + p];

    float lg[9];
    float m = -1e30f;
#pragma unroll
    for (int t = 0; t < 9; ++t) {
        float s = sb[t];
#pragma unroll
        for (int c = 0; c < 32; ++c) s = fmaf(sw[t * 32 + c], v[c], s);
        lg[t] = s;
        m = fmaxf(m, s);
    }
    float sum = 0.f;
#pragma unroll
    for (int t = 0; t < 9; ++t) {
        lg[t] = __expf(lg[t] - m);
        sum += lg[t];
    }
    float inv = 1.f / sum;
#pragma unroll
    for (int t = 0; t < 9; ++t)
        kern[((size_t)(b * 9 + t)) * HWSZ + p] = lg[t] * inv;
}

// ---------------------------------------------------------------------------
// Adaptive 3x3 filter apply (fp32, exact)
// ---------------------------------------------------------------------------
__global__ void deblur_kernel(const float* __restrict__ x,
                              const float* __restrict__ kern,
                              float* __restrict__ out) {
    int idx = blockIdx.x * blockDim.x + threadIdx.x;
    if (idx >= BB * CC * HWSZ) return;
    int w_ = idx % WW;
    int h  = (idx / WW) % HH;
    int c  = (idx / HWSZ) % CC;
    int b  = idx / (HWSZ * CC);

    const float* kb = kern + (size_t)(b * 9) * HWSZ + h * WW + w_;
    const float* xb = x + (size_t)(b * CC + c) * HWSZ;
    float sum = 0.f;
    int t = 0;
#pragma unroll
    for (int dy = 0; dy < 3; ++dy) {
#pragma unroll
        for (int dx = 0; dx < 3; ++dx) {
            int hh = h + dy - 1, ww2 = w_ + dx - 1;
            float xv = ((unsigned)hh < (unsigned)HH && (unsigned)ww2 < (unsigned)WW)
                           ? xb[hh * WW + ww2] : 0.f;
            sum = fmaf(kb[(size_t)t * HWSZ], xv, sum);
            ++t;
        }
    }
    out[idx] = sum;
}

// ---------------------------------------------------------------------------
extern "C" void kernel_launch(void* const* d_in, const int* in_sizes, int n_in,
                              void* d_out, int out_size, void* d_ws, size_t ws_size,
                              hipStream_t stream) {
    const float* x   = (const float*)d_in[0];
    const float* w1  = (const float*)d_in[1];
    const float* b1  = (const float*)d_in[2];
    const float* w2  = (const float*)d_in[3];
    const float* b2  = (const float*)d_in[4];
    const float* w3  = (const float*)d_in[5];
    const float* b3  = (const float*)d_in[6];
    const float* f1  = (const float*)d_in[7];
    const float* fb1 = (const float*)d_in[8];
    const float* f2  = (const float*)d_in[9];
    const float* fb2 = (const float*)d_in[10];
    float* out = (float*)d_out;

    // workspace layout
    float* ws = (float*)d_ws;
    const size_t SZ_FULL = (size_t)BB * CC * HWSZ;        // 18,874,368 floats
    float* regionA = ws;                                  // t1 then t3
    float* regionB = regionA + SZ_FULL;                   // t2 then t4
    float* kern    = regionB + SZ_FULL;                   // (B,9,H,W)
    short* wp1     = (short*)(kern + (size_t)BB * 9 * HWSZ);
    short* wp2     = wp1 + 9 * 4 * 64 * 32;               // 73,728
    short* wpf1    = wp2 + 9 * 2 * 32 * 32;               // 18,432
    short* wpf2    = wpf1 + 9 * 4 * 128 * 32;             // 147,456

    float* t1 = regionA;   // (B,64,H,W)
    float* t2 = regionB;   // (B,32,H,W)
    float* t3 = regionA;   // (B,128,H,W)  overwrites t1 (dead)
    float* t4 = regionB;   // (B,128,H,W)  overwrites t2 (dead)

    // weight prep (fp32 -> bf16, [tap][ck][co][ci])
    {
        int n1 = 9 * 4 * 64 * 32, n2 = 9 * 2 * 32 * 32, nf = 9 * 4 * 128 * 32;
        prep_w_kernel<<<(n1 + 255) / 256, 256, 0, stream>>>(w1, wp1, 128, 64, n1);
        prep_w_kernel<<<(n2 + 255) / 256, 256, 0, stream>>>(w2, wp2, 64, 32, n2);
        prep_w_kernel<<<(nf + 255) / 256, 256, 0, stream>>>(f1, wpf1, 128, 128, nf);
        prep_w_kernel<<<(nf + 255) / 256, 256, 0, stream>>>(f2, wpf2, 128, 128, nf);
    }

    // conv1: 128 -> 64, relu   (4 waves: 1x4 wave grid, each 4m x 3n tiles)
    conv3x3_mfma<128, 64, 1, 4, 4, 3, true>
        <<<dim3(HH, BB), 256, 0, stream>>>(x, wp1, b1, t1);
    // conv2: 64 -> 32, relu    (4 waves: 1x4, each 2m x 3n)
    conv3x3_mfma<64, 32, 1, 4, 2, 3, true>
        <<<dim3(HH, BB), 256, 0, stream>>>(t1, wp2, b2, t2);
    // conv3 1x1 + softmax -> kern
    conv1x1_softmax_kernel<<<(NPIX + 255) / 256, 256, 0, stream>>>(t2, w3, b3, kern);
    // adaptive filter apply
    deblur_kernel<<<((int)((size_t)BB * CC * HWSZ) + 255) / 256, 256, 0, stream>>>(x, kern, t3);
    // f1: 128 -> 128, relu     (8 waves: 2x4, each 4m x 3n)
    conv3x3_mfma<128, 128, 2, 4, 4, 3, true>
        <<<dim3(HH, BB), 512, 0, stream>>>(t3, wpf1, fb1, t4);
    // f2: 128 -> 128, no relu -> final output
    conv3x3_mfma<128, 128, 2, 4, 4, 3, false>
        <<<dim3(HH, BB), 512, 0, stream>>>(t4, wpf2, fb2, out);
}

// Round 3
// 439.925 us; speedup vs baseline: 4.8709x; 1.0639x over previous
//
#include <hip/hip_runtime.h>
#include <math.h>

// Problem constants (B, C, H, W) = (4, 128, 192, 192)
#define BB 4
#define CC 128
#define HH 192
#define WW 192
#define HWSZ (HH * WW)          // 36864
#define NPIX (BB * HWSZ)        // 147456
#define PD 194                  // padded H/W for bf16 activation buffers

typedef __attribute__((ext_vector_type(8))) short short8;
typedef __attribute__((ext_vector_type(4))) short short4v;
typedef __attribute__((ext_vector_type(4))) float float4v;

// fp32 -> bf16, round-to-nearest-even
__device__ __forceinline__ short f2bf(float f) {
    unsigned u = __float_as_uint(f);
    u += 0x7FFF + ((u >> 16) & 1);
    return (short)(u >> 16);
}
__device__ __forceinline__ float bf2f(short s) {
    return __uint_as_float(((unsigned)(unsigned short)s) << 16);
}

// ---------------------------------------------------------------------------
// Weight prep:  w[co][cin][ky][kx] fp32  ->  wp[tap][ck][co][ci] bf16
// (tap = ky*3+kx, cin = ck*32+ci).  A-frag loads become contiguous 16B/lane.
// ---------------------------------------------------------------------------
__global__ void prep_w_kernel(const float* __restrict__ w,
                              short* __restrict__ wp,
                              int CIN, int COUT, int total) {
    int idx = blockIdx.x * blockDim.x + threadIdx.x;
    if (idx >= total) return;
    int ci  = idx & 31;
    int co  = (idx >> 5) % COUT;
    int rem = (idx >> 5) / COUT;
    int CKN = CIN / 32;
    int ck  = rem % CKN;
    int tap = rem / CKN;
    int cin = ck * 32 + ci;
    wp[idx] = f2bf(w[(co * CIN + cin) * 9 + tap]);
}

// ---------------------------------------------------------------------------
// Zero the borders of the three padded bf16 activation buffers (ws is
// re-poisoned to 0xAA before every launch, so this must run every call).
// Each buffer: 4 b x 16 cg x 194x194 x 8c units; border = 772 units/(b,cg).
// ---------------------------------------------------------------------------
__global__ void zero_pads_kernel(short* __restrict__ p0,
                                 short* __restrict__ p1,
                                 short* __restrict__ p2) {
    int idx = blockIdx.x * blockDim.x + threadIdx.x;
    if (idx >= 3 * 64 * 772) return;
    int e   = idx % 772;
    int bc  = (idx / 772) % 64;
    int buf = idx / (772 * 64);
    short* base = (buf == 0) ? p0 : (buf == 1) ? p1 : p2;
    int row, col;
    if (e < 194)      { row = 0;   col = e; }
    else if (e < 388) { row = 193; col = e - 194; }
    else { int e2 = e - 388; row = 1 + (e2 >> 1); col = (e2 & 1) * 193; }
    short8 z = {0, 0, 0, 0, 0, 0, 0, 0};
    *(short8*)&base[(((size_t)bc * PD + row) * PD + col) * 8] = z;
}

// ---------------------------------------------------------------------------
// x fp32 NCHW -> padded bf16 8c-blocked [b][cg][h+1][w+1][8]
// ---------------------------------------------------------------------------
__global__ void x_prep_kernel(const float* __restrict__ x,
                              short* __restrict__ xp) {
    int idx = blockIdx.x * blockDim.x + threadIdx.x;
    if (idx >= BB * 16 * HWSZ) return;
    int w  = idx % WW;
    int h  = (idx / WW) % HH;
    int cg = (idx / HWSZ) % 16;
    int b  = idx / (HWSZ * 16);
    const float* p = x + ((size_t)(b * CC + cg * 8) * HH + h) * WW + w;
    short8 pk;
#pragma unroll
    for (int j = 0; j < 8; ++j) pk[j] = f2bf(p[(size_t)j * HWSZ]);
    *(short8*)&xp[((((size_t)b * 16 + cg) * PD + h + 1) * PD + (w + 1)) * 8] = pk;
}

// ---------------------------------------------------------------------------
// Implicit-GEMM 3x3 conv, bf16 MFMA 16x16x32, fp32 accumulate.
// Input: padded bf16 8c-blocked.  Staging: pure global_load_lds DMA (16B),
// LDS layout [row 0..2][g 0..3][col 0..193][8c] == staging unit order.
// Output: padded bf16 8c-blocked (OUT_F32=false) or fp32 NCHW (final conv).
// ---------------------------------------------------------------------------
template <int CIN, int COUT, int WAVES_M, int WAVES_N, int WM, int WN,
          bool RELU, bool OUT_F32>
__global__ __launch_bounds__(WAVES_M * WAVES_N * 64)
void conv3x3_mfma(const short* __restrict__ in,
                  const short* __restrict__ wp,   // [tap][ck][co][32ci] bf16
                  const float* __restrict__ bias,
                  void* __restrict__ outv) {
    constexpr int CKN   = CIN / 32;
    constexpr int CG_IN = CIN / 8;
    constexpr int CGO   = COUT / 8;
    constexpr int NT    = WAVES_M * WAVES_N * 64;
    static_assert(WAVES_M * WM * 16 == COUT, "M tiling");
    static_assert(WAVES_N * WN * 16 == 192, "N tiling");

    __shared__ __align__(16) short s_x[3 * 4 * PD * 8];   // 37,248 B

    const int tid  = threadIdx.x;
    const int h    = blockIdx.x;
    const int b    = blockIdx.y;
    const int lane = tid & 63;
    const int wv   = tid >> 6;
    const int wv_m = wv % WAVES_M;
    const int wv_n = wv / WAVES_M;
    const int ln15 = lane & 15;
    const int lg   = lane >> 4;              // k-group 0..3

    float4v acc[WM][WN];
#pragma unroll
    for (int mi = 0; mi < WM; ++mi)
#pragma unroll
        for (int ni = 0; ni < WN; ++ni)
            acc[mi][ni] = (float4v){0.f, 0.f, 0.f, 0.f};

    for (int ck = 0; ck < CKN; ++ck) {
        // ---- stage input slab: DMA, unit i -> LDS i*16, lane-consecutive ----
        for (int i = tid; i < 3 * 4 * PD; i += NT) {
            int col = i % PD;
            int rem = i / PD;
            int g   = rem & 3;
            int row = rem >> 2;
            const short* gp = in +
                ((((size_t)b * CG_IN + ck * 4 + g) * PD + (h + row)) * PD + col) * 8;
            __builtin_amdgcn_global_load_lds(
                (const __attribute__((address_space(1))) void*)gp,
                (__attribute__((address_space(3))) void*)&s_x[i * 8], 16, 0, 0);
        }
        __syncthreads();

        // ---- 9 taps: A prefetched one tap ahead, B from LDS, MFMA ----
        short8 a_cur[WM], a_nxt[WM];
#pragma unroll
        for (int mi = 0; mi < WM; ++mi) {
            int co = (wv_m * WM + mi) * 16 + ln15;
            a_cur[mi] = *(const short8*)&wp[(((size_t)0 * CKN + ck) * COUT + co) * 32 + lg * 8];
        }
#pragma unroll
        for (int tap = 0; tap < 9; ++tap) {
            const int dy = tap / 3, dx = tap % 3;
            if (tap < 8) {
#pragma unroll
                for (int mi = 0; mi < WM; ++mi) {
                    int co = (wv_m * WM + mi) * 16 + ln15;
                    a_nxt[mi] = *(const short8*)
                        &wp[(((size_t)(tap + 1) * CKN + ck) * COUT + co) * 32 + lg * 8];
                }
            }
            short8 bfr[WN];
#pragma unroll
            for (int ni = 0; ni < WN; ++ni) {
                int col = (wv_n * WN + ni) * 16 + ln15 + dx;   // padded col
                bfr[ni] = *(const short8*)&s_x[((dy * 4 + lg) * PD + col) * 8];
            }
#pragma unroll
            for (int mi = 0; mi < WM; ++mi)
#pragma unroll
                for (int ni = 0; ni < WN; ++ni)
                    acc[mi][ni] = __builtin_amdgcn_mfma_f32_16x16x32_bf16(
                        a_cur[mi], bfr[ni], acc[mi][ni], 0, 0, 0);
            if (tap < 8) {
#pragma unroll
                for (int mi = 0; mi < WM; ++mi) a_cur[mi] = a_nxt[mi];
            }
        }
        __syncthreads();
    }

    // ---- epilogue: C layout col=lane&15 (pixel), row=lg*4+reg (cout) ----
    if (OUT_F32) {
        float* out = (float*)outv;
#pragma unroll
        for (int mi = 0; mi < WM; ++mi) {
            int co0 = (wv_m * WM + mi) * 16 + lg * 4;
#pragma unroll
            for (int r = 0; r < 4; ++r) {
                int co = co0 + r;
                float bv = bias[co];
#pragma unroll
                for (int ni = 0; ni < WN; ++ni) {
                    int wcol = (wv_n * WN + ni) * 16 + ln15;
                    float v = acc[mi][ni][r] + bv;
                    if (RELU) v = fmaxf(v, 0.f);
                    out[((size_t)(b * COUT + co) * HH + h) * WW + wcol] = v;
                }
            }
        }
    } else {
        short* out = (short*)outv;
#pragma unroll
        for (int mi = 0; mi < WM; ++mi) {
            int co0 = (wv_m * WM + mi) * 16 + lg * 4;    // 4 consecutive couts
            int cg  = co0 >> 3;
            int sub = co0 & 7;                           // 0 or 4
#pragma unroll
            for (int ni = 0; ni < WN; ++ni) {
                int wcol = (wv_n * WN + ni) * 16 + ln15;
                short4v pk;
#pragma unroll
                for (int r = 0; r < 4; ++r) {
                    float v = acc[mi][ni][r] + bias[co0 + r];
                    if (RELU) v = fmaxf(v, 0.f);
                    pk[r] = f2bf(v);
                }
                *(short4v*)&out[((((size_t)b * CGO + cg) * PD + (h + 1)) * PD +
                                 (wcol + 1)) * 8 + sub] = pk;
            }
        }
    }
}

// ---------------------------------------------------------------------------
// conv1x1 (32 -> 9 logits) + softmax; reads bf16 8c-blocked padded t2.
// ---------------------------------------------------------------------------
__global__ void conv1x1_softmax_kernel(const short* __restrict__ t2,
                                       const float* __restrict__ w3,   // (9,32)
                                       const float* __restrict__ b3,
                                       float* __restrict__ kern) {     // (B,9,H,W)
    __shared__ float sw[9 * 32];
    __shared__ float sb[9];
    for (int i = threadIdx.x; i < 9 * 32; i += blockDim.x) sw[i] = w3[i];
    if (threadIdx.x < 9) sb[threadIdx.x] = b3[threadIdx.x];
    __syncthreads();

    int idx = blockIdx.x * blockDim.x + threadIdx.x;
    if (idx >= NPIX) return;
    int b = idx / HWSZ;
    int p = idx % HWSZ;
    int h = p / WW, w = p % WW;

    float v[32];
#pragma unroll
    for (int cg = 0; cg < 4; ++cg) {
        short8 pk = *(const short8*)
            &t2[((((size_t)b * 4 + cg) * PD + h + 1) * PD + (w + 1)) * 8];
#pragma unroll
        for (int j = 0; j < 8; ++j) v[cg * 8 + j] = bf2f(pk[j]);
    }

    float lg[9];
    float m = -1e30f;
#pragma unroll
    for (int t = 0; t < 9; ++t) {
        float s = sb[t];
#pragma unroll
        for (int c = 0; c < 32; ++c) s = fmaf(sw[t * 32 + c], v[c], s);
        lg[t] = s;
        m = fmaxf(m, s);
    }
    float sum = 0.f;
#pragma unroll
    for (int t = 0; t < 9; ++t) {
        lg[t] = __expf(lg[t] - m);
        sum += lg[t];
    }
    float inv = 1.f / sum;
#pragma unroll
    for (int t = 0; t < 9; ++t)
        kern[((size_t)(b * 9 + t)) * HWSZ + p] = lg[t] * inv;
}

// ---------------------------------------------------------------------------
// Adaptive 3x3 filter apply: fp32 x (exact) * fp32 kernel -> bf16 8c t3.
// One thread = 8 channels at one pixel (kern loads amortized over 8 ch).
// ---------------------------------------------------------------------------
__global__ void deblur_kernel(const float* __restrict__ x,
                              const float* __restrict__ kern,
                              short* __restrict__ t3) {
    int idx = blockIdx.x * blockDim.x + threadIdx.x;
    if (idx >= BB * 16 * HWSZ) return;
    int w  = idx % WW;
    int h  = (idx / WW) % HH;
    int cg = (idx / HWSZ) % 16;
    int b  = idx / (HWSZ * 16);

    const float* kb = kern + (size_t)(b * 9) * HWSZ + h * WW + w;
    float kv[9];
#pragma unroll
    for (int t = 0; t < 9; ++t) kv[t] = kb[(size_t)t * HWSZ];

    const float* xb = x + (size_t)(b * CC + cg * 8) * HWSZ;
    float s[8] = {0.f, 0.f, 0.f, 0.f, 0.f, 0.f, 0.f, 0.f};
    int t = 0;
#pragma unroll
    for (int dy = 0; dy < 3; ++dy) {
#pragma unroll
        for (int dx = 0; dx < 3; ++dx) {
            int hh = h + dy - 1, ww2 = w + dx - 1;
            if ((unsigned)hh < (unsigned)HH && (unsigned)ww2 < (unsigned)WW) {
                const float* xp = xb + hh * WW + ww2;
#pragma unroll
                for (int j = 0; j < 8; ++j)
                    s[j] = fmaf(kv[t], xp[(size_t)j * HWSZ], s[j]);
            }
            ++t;
        }
    }
    short8 pk;
#pragma unroll
    for (int j = 0; j < 8; ++j) pk[j] = f2bf(s[j]);
    *(short8*)&t3[((((size_t)b * 16 + cg) * PD + h + 1) * PD + (w + 1)) * 8] = pk;
}

// ---------------------------------------------------------------------------
extern "C" void kernel_launch(void* const* d_in, const int* in_sizes, int n_in,
                              void* d_out, int out_size, void* d_ws, size_t ws_size,
                              hipStream_t stream) {
    const float* x   = (const float*)d_in[0];
    const float* w1  = (const float*)d_in[1];
    const float* b1  = (const float*)d_in[2];
    const float* w2  = (const float*)d_in[3];
    const float* b2  = (const float*)d_in[4];
    const float* w3  = (const float*)d_in[5];
    const float* b3  = (const float*)d_in[6];
    const float* f1  = (const float*)d_in[7];
    const float* fb1 = (const float*)d_in[8];
    const float* f2  = (const float*)d_in[9];
    const float* fb2 = (const float*)d_in[10];
    float* out = (float*)d_out;

    // workspace layout (bf16 activation buffers are padded 8c-blocked)
    const size_t ACT_SZ = (size_t)BB * 16 * PD * PD * 8;   // shorts, 128ch buffer
    short* xpad    = (short*)d_ws;
    short* regionA = xpad + ACT_SZ;       // t1 (64ch) then t3 (128ch)
    short* regionB = regionA + ACT_SZ;    // t2 (32ch) then t4 (128ch)
    float* kern    = (float*)(regionB + ACT_SZ);           // (B,9,H,W) fp32
    short* wp1     = (short*)(kern + (size_t)BB * 9 * HWSZ);
    short* wp2     = wp1 + 9 * 4 * 64 * 32;
    short* wpf1    = wp2 + 9 * 2 * 32 * 32;
    short* wpf2    = wpf1 + 9 * 4 * 128 * 32;

    short* t1 = regionA;
    short* t2 = regionB;
    short* t3 = regionA;   // overwrites t1 (dead)
    short* t4 = regionB;   // overwrites t2 (dead)

    // border zeroing + x conversion + weight prep
    {
        int nz = 3 * 64 * 772;
        zero_pads_kernel<<<(nz + 255) / 256, 256, 0, stream>>>(xpad, regionA, regionB);
        int nx = BB * 16 * HWSZ;
        x_prep_kernel<<<(nx + 255) / 256, 256, 0, stream>>>(x, xpad);
        int n1 = 9 * 4 * 64 * 32, n2 = 9 * 2 * 32 * 32, nf = 9 * 4 * 128 * 32;
        prep_w_kernel<<<(n1 + 255) / 256, 256, 0, stream>>>(w1, wp1, 128, 64, n1);
        prep_w_kernel<<<(n2 + 255) / 256, 256, 0, stream>>>(w2, wp2, 64, 32, n2);
        prep_w_kernel<<<(nf + 255) / 256, 256, 0, stream>>>(f1, wpf1, 128, 128, nf);
        prep_w_kernel<<<(nf + 255) / 256, 256, 0, stream>>>(f2, wpf2, 128, 128, nf);
    }

    // conv1: 128 -> 64, relu
    conv3x3_mfma<128, 64, 2, 4, 2, 3, true, false>
        <<<dim3(HH, BB), 512, 0, stream>>>(xpad, wp1, b1, t1);
    // conv2: 64 -> 32, relu
    conv3x3_mfma<64, 32, 2, 4, 1, 3, true, false>
        <<<dim3(HH, BB), 512, 0, stream>>>(t1, wp2, b2, t2);
    // conv3 1x1 + softmax -> kern
    conv1x1_softmax_kernel<<<(NPIX + 255) / 256, 256, 0, stream>>>(t2, w3, b3, kern);
    // adaptive filter apply (exact fp32 x) -> bf16 t3
    {
        int nd = BB * 16 * HWSZ;
        deblur_kernel<<<(nd + 255) / 256, 256, 0, stream>>>(x, kern, t3);
    }
    // f1: 128 -> 128, relu
    conv3x3_mfma<128, 128, 2, 4, 4, 3, true, false>
        <<<dim3(HH, BB), 512, 0, stream>>>(t3, wpf1, fb1, t4);
    // f2: 128 -> 128, no relu -> final fp32 output
    conv3x3_mfma<128, 128, 2, 4, 4, 3, false, true>
        <<<dim3(HH, BB), 512, 0, stream>>>(t4, wpf2, fb2, out);
}

// Round 4
// 430.862 us; speedup vs baseline: 4.9733x; 1.0210x over previous
//
#include <hip/hip_runtime.h>
#include <math.h>

// Problem constants (B, C, H, W) = (4, 128, 192, 192)
#define BB 4
#define CC 128
#define HH 192
#define WW 192
#define HWSZ (HH * WW)          // 36864
#define NPIX (BB * HWSZ)        // 147456
#define PD 194                  // padded H/W for bf16 activation buffers

typedef __attribute__((ext_vector_type(8))) short short8;
typedef __attribute__((ext_vector_type(4))) short short4v;
typedef __attribute__((ext_vector_type(4))) float float4v;

// fp32 -> bf16, round-to-nearest-even
__device__ __forceinline__ short f2bf(float f) {
    unsigned u = __float_as_uint(f);
    u += 0x7FFF + ((u >> 16) & 1);
    return (short)(u >> 16);
}
__device__ __forceinline__ float bf2f(short s) {
    return __uint_as_float(((unsigned)(unsigned short)s) << 16);
}

// ---------------------------------------------------------------------------
// Weight prep:  w[co][cin][ky][kx] fp32  ->  wp[tap][ck][co][ci] bf16
// ---------------------------------------------------------------------------
__global__ void prep_w_kernel(const float* __restrict__ w,
                              short* __restrict__ wp,
                              int CIN, int COUT, int total) {
    int idx = blockIdx.x * blockDim.x + threadIdx.x;
    if (idx >= total) return;
    int ci  = idx & 31;
    int co  = (idx >> 5) % COUT;
    int rem = (idx >> 5) / COUT;
    int CKN = CIN / 32;
    int ck  = rem % CKN;
    int tap = rem / CKN;
    int cin = ck * 32 + ci;
    wp[idx] = f2bf(w[(co * CIN + cin) * 9 + tap]);
}

// ---------------------------------------------------------------------------
// Zero the borders of the three padded bf16 activation buffers.
// ---------------------------------------------------------------------------
__global__ void zero_pads_kernel(short* __restrict__ p0,
                                 short* __restrict__ p1,
                                 short* __restrict__ p2) {
    int idx = blockIdx.x * blockDim.x + threadIdx.x;
    if (idx >= 3 * 64 * 772) return;
    int e   = idx % 772;
    int bc  = (idx / 772) % 64;
    int buf = idx / (772 * 64);
    short* base = (buf == 0) ? p0 : (buf == 1) ? p1 : p2;
    int row, col;
    if (e < 194)      { row = 0;   col = e; }
    else if (e < 388) { row = 193; col = e - 194; }
    else { int e2 = e - 388; row = 1 + (e2 >> 1); col = (e2 & 1) * 193; }
    short8 z = {0, 0, 0, 0, 0, 0, 0, 0};
    *(short8*)&base[(((size_t)bc * PD + row) * PD + col) * 8] = z;
}

// ---------------------------------------------------------------------------
// x fp32 NCHW -> padded bf16 8c-blocked [b][cg][h+1][w+1][8]
// ---------------------------------------------------------------------------
__global__ void x_prep_kernel(const float* __restrict__ x,
                              short* __restrict__ xp) {
    int idx = blockIdx.x * blockDim.x + threadIdx.x;
    if (idx >= BB * 16 * HWSZ) return;
    int w  = idx % WW;
    int h  = (idx / WW) % HH;
    int cg = (idx / HWSZ) % 16;
    int b  = idx / (HWSZ * 16);
    const float* p = x + ((size_t)(b * CC + cg * 8) * HH + h) * WW + w;
    short8 pk;
#pragma unroll
    for (int j = 0; j < 8; ++j) pk[j] = f2bf(p[(size_t)j * HWSZ]);
    *(short8*)&xp[((((size_t)b * 16 + cg) * PD + h + 1) * PD + (w + 1)) * 8] = pk;
}

// ---------------------------------------------------------------------------
// Implicit-GEMM 3x3 conv, bf16 MFMA 16x16x32, fp32 accumulate.
// BARRIER-FREE: no LDS. B-fragments are read directly from the padded
// 8c-blocked bf16 global buffer (address maps 1:1 to what the LDS copy held);
// A and B are ping-pong prefetched one K-step ahead; waves are fully
// independent -> scheduler interleaves MFMA with loads across 24 waves/CU.
// ---------------------------------------------------------------------------
template <int CIN, int COUT, int WAVES_M, int WAVES_N, int WM, int WN,
          bool RELU, bool OUT_F32>
__global__ __launch_bounds__(WAVES_M * WAVES_N * 64, 4)
void conv3x3_direct(const short* __restrict__ in,
                    const short* __restrict__ wp,   // [tap][ck][co][32ci] bf16
                    const float* __restrict__ bias,
                    void* __restrict__ outv) {
    constexpr int CKN   = CIN / 32;
    constexpr int CG_IN = CIN / 8;
    constexpr int CGO   = COUT / 8;
    constexpr int KT    = CKN * 9;
    constexpr int NPX   = WAVES_N * WN * 16;   // pixels per block
    static_assert(WAVES_M * WM * 16 == COUT, "M tiling");

    const int tid  = threadIdx.x;
    const int h    = blockIdx.y;
    const int b    = blockIdx.z;
    const int px0  = blockIdx.x * NPX;
    const int lane = tid & 63;
    const int wv   = tid >> 6;
    const int wv_m = wv % WAVES_M;
    const int wv_n = wv / WAVES_M;
    const int ln15 = lane & 15;
    const int lg   = lane >> 4;              // k-subgroup 0..3 (8 cins each)

    float4v acc[WM][WN];
#pragma unroll
    for (int mi = 0; mi < WM; ++mi)
#pragma unroll
        for (int ni = 0; ni < WN; ++ni)
            acc[mi][ni] = (float4v){0.f, 0.f, 0.f, 0.f};

    short8 Ab[2][WM], Bb[2][WN];

    auto loadA = [&](int kt, short8* dst) {
        const int ck = kt / 9, tap = kt % 9;
#pragma unroll
        for (int mi = 0; mi < WM; ++mi) {
            int co = (wv_m * WM + mi) * 16 + ln15;
            dst[mi] = *(const short8*)
                &wp[(((size_t)tap * CKN + ck) * COUT + co) * 32 + lg * 8];
        }
    };
    auto loadB = [&](int kt, short8* dst) {
        const int ck = kt / 9, tap = kt % 9;
        const int dy = tap / 3, dx = tap % 3;
#pragma unroll
        for (int ni = 0; ni < WN; ++ni) {
            int col = px0 + (wv_n * WN + ni) * 16 + ln15 + dx;
            dst[ni] = *(const short8*)
                &in[((((size_t)b * CG_IN + ck * 4 + lg) * PD + (h + dy)) * PD + col) * 8];
        }
    };

    loadA(0, Ab[0]);
    loadB(0, Bb[0]);
#pragma unroll
    for (int kt = 0; kt < KT; ++kt) {
        if (kt + 1 < KT) {
            loadA(kt + 1, Ab[(kt + 1) & 1]);
            loadB(kt + 1, Bb[(kt + 1) & 1]);
        }
#pragma unroll
        for (int mi = 0; mi < WM; ++mi)
#pragma unroll
            for (int ni = 0; ni < WN; ++ni)
                acc[mi][ni] = __builtin_amdgcn_mfma_f32_16x16x32_bf16(
                    Ab[kt & 1][mi], Bb[kt & 1][ni], acc[mi][ni], 0, 0, 0);
    }

    // ---- epilogue: C layout col=lane&15 (pixel), row=lg*4+reg (cout) ----
    if (OUT_F32) {
        float* out = (float*)outv;
#pragma unroll
        for (int mi = 0; mi < WM; ++mi) {
            int co0 = (wv_m * WM + mi) * 16 + lg * 4;
#pragma unroll
            for (int r = 0; r < 4; ++r) {
                int co = co0 + r;
                float bv = bias[co];
#pragma unroll
                for (int ni = 0; ni < WN; ++ni) {
                    int wcol = px0 + (wv_n * WN + ni) * 16 + ln15;
                    float v = acc[mi][ni][r] + bv;
                    if (RELU) v = fmaxf(v, 0.f);
                    out[((size_t)(b * COUT + co) * HH + h) * WW + wcol] = v;
                }
            }
        }
    } else {
        short* out = (short*)outv;
#pragma unroll
        for (int mi = 0; mi < WM; ++mi) {
            int co0 = (wv_m * WM + mi) * 16 + lg * 4;    // 4 consecutive couts
            int cg  = co0 >> 3;
            int sub = co0 & 7;                           // 0 or 4
#pragma unroll
            for (int ni = 0; ni < WN; ++ni) {
                int wcol = px0 + (wv_n * WN + ni) * 16 + ln15;
                short4v pk;
#pragma unroll
                for (int r = 0; r < 4; ++r) {
                    float v = acc[mi][ni][r] + bias[co0 + r];
                    if (RELU) v = fmaxf(v, 0.f);
                    pk[r] = f2bf(v);
                }
                *(short4v*)&out[((((size_t)b * CGO + cg) * PD + (h + 1)) * PD +
                                 (wcol + 1)) * 8 + sub] = pk;
            }
        }
    }
}

// ---------------------------------------------------------------------------
// conv1x1 (32 -> 9 logits) + softmax; reads bf16 8c-blocked padded t2.
// ---------------------------------------------------------------------------
__global__ void conv1x1_softmax_kernel(const short* __restrict__ t2,
                                       const float* __restrict__ w3,   // (9,32)
                                       const float* __restrict__ b3,
                                       float* __restrict__ kern) {     // (B,9,H,W)
    __shared__ float sw[9 * 32];
    __shared__ float sb[9];
    for (int i = threadIdx.x; i < 9 * 32; i += blockDim.x) sw[i] = w3[i];
    if (threadIdx.x < 9) sb[threadIdx.x] = b3[threadIdx.x];
    __syncthreads();

    int idx = blockIdx.x * blockDim.x + threadIdx.x;
    if (idx >= NPIX) return;
    int b = idx / HWSZ;
    int p = idx % HWSZ;
    int h = p / WW, w = p % WW;

    float v[32];
#pragma unroll
    for (int cg = 0; cg < 4; ++cg) {
        short8 pk = *(const short8*)
            &t2[((((size_t)b * 4 + cg) * PD + h + 1) * PD + (w + 1)) * 8];
#pragma unroll
        for (int j = 0; j < 8; ++j) v[cg * 8 + j] = bf2f(pk[j]);
    }

    float lg[9];
    float m = -1e30f;
#pragma unroll
    for (int t = 0; t < 9; ++t) {
        float s = sb[t];
#pragma unroll
        for (int c = 0; c < 32; ++c) s = fmaf(sw[t * 32 + c], v[c], s);
        lg[t] = s;
        m = fmaxf(m, s);
    }
    float sum = 0.f;
#pragma unroll
    for (int t = 0; t < 9; ++t) {
        lg[t] = __expf(lg[t] - m);
        sum += lg[t];
    }
    float inv = 1.f / sum;
#pragma unroll
    for (int t = 0; t < 9; ++t)
        kern[((size_t)(b * 9 + t)) * HWSZ + p] = lg[t] * inv;
}

// ---------------------------------------------------------------------------
// Adaptive 3x3 filter apply: fp32 x (exact) * fp32 kernel -> bf16 8c t3.
// ---------------------------------------------------------------------------
__global__ void deblur_kernel(const float* __restrict__ x,
                              const float* __restrict__ kern,
                              short* __restrict__ t3) {
    int idx = blockIdx.x * blockDim.x + threadIdx.x;
    if (idx >= BB * 16 * HWSZ) return;
    int w  = idx % WW;
    int h  = (idx / WW) % HH;
    int cg = (idx / HWSZ) % 16;
    int b  = idx / (HWSZ * 16);

    const float* kb = kern + (size_t)(b * 9) * HWSZ + h * WW + w;
    float kv[9];
#pragma unroll
    for (int t = 0; t < 9; ++t) kv[t] = kb[(size_t)t * HWSZ];

    const float* xb = x + (size_t)(b * CC + cg * 8) * HWSZ;
    float s[8] = {0.f, 0.f, 0.f, 0.f, 0.f, 0.f, 0.f, 0.f};
    int t = 0;
#pragma unroll
    for (int dy = 0; dy < 3; ++dy) {
#pragma unroll
        for (int dx = 0; dx < 3; ++dx) {
            int hh = h + dy - 1, ww2 = w + dx - 1;
            if ((unsigned)hh < (unsigned)HH && (unsigned)ww2 < (unsigned)WW) {
                const float* xp = xb + hh * WW + ww2;
#pragma unroll
                for (int j = 0; j < 8; ++j)
                    s[j] = fmaf(kv[t], xp[(size_t)j * HWSZ], s[j]);
            }
            ++t;
        }
    }
    short8 pk;
#pragma unroll
    for (int j = 0; j < 8; ++j) pk[j] = f2bf(s[j]);
    *(short8*)&t3[((((size_t)b * 16 + cg) * PD + h + 1) * PD + (w + 1)) * 8] = pk;
}

// ---------------------------------------------------------------------------
extern "C" void kernel_launch(void* const* d_in, const int* in_sizes, int n_in,
                              void* d_out, int out_size, void* d_ws, size_t ws_size,
                              hipStream_t stream) {
    const float* x   = (const float*)d_in[0];
    const float* w1  = (const float*)d_in[1];
    const float* b1  = (const float*)d_in[2];
    const float* w2  = (const float*)d_in[3];
    const float* b2  = (const float*)d_in[4];
    const float* w3  = (const float*)d_in[5];
    const float* b3  = (const float*)d_in[6];
    const float* f1  = (const float*)d_in[7];
    const float* fb1 = (const float*)d_in[8];
    const float* f2  = (const float*)d_in[9];
    const float* fb2 = (const float*)d_in[10];
    float* out = (float*)d_out;

    // workspace layout (bf16 activation buffers are padded 8c-blocked)
    const size_t ACT_SZ = (size_t)BB * 16 * PD * PD * 8;   // shorts, 128ch buffer
    short* xpad    = (short*)d_ws;
    short* regionA = xpad + ACT_SZ;       // t1 (64ch) then t3 (128ch)
    short* regionB = regionA + ACT_SZ;    // t2 (32ch) then t4 (128ch)
    float* kern    = (float*)(regionB + ACT_SZ);           // (B,9,H,W) fp32
    short* wp1     = (short*)(kern + (size_t)BB * 9 * HWSZ);
    short* wp2     = wp1 + 9 * 4 * 64 * 32;
    short* wpf1    = wp2 + 9 * 2 * 32 * 32;
    short* wpf2    = wpf1 + 9 * 4 * 128 * 32;

    short* t1 = regionA;
    short* t2 = regionB;
    short* t3 = regionA;   // overwrites t1 (dead)
    short* t4 = regionB;   // overwrites t2 (dead)

    // border zeroing + x conversion + weight prep
    {
        int nz = 3 * 64 * 772;
        zero_pads_kernel<<<(nz + 255) / 256, 256, 0, stream>>>(xpad, regionA, regionB);
        int nx = BB * 16 * HWSZ;
        x_prep_kernel<<<(nx + 255) / 256, 256, 0, stream>>>(x, xpad);
        int n1 = 9 * 4 * 64 * 32, n2 = 9 * 2 * 32 * 32, nf = 9 * 4 * 128 * 32;
        prep_w_kernel<<<(n1 + 255) / 256, 256, 0, stream>>>(w1, wp1, 128, 64, n1);
        prep_w_kernel<<<(n2 + 255) / 256, 256, 0, stream>>>(w2, wp2, 64, 32, n2);
        prep_w_kernel<<<(nf + 255) / 256, 256, 0, stream>>>(f1, wpf1, 128, 128, nf);
        prep_w_kernel<<<(nf + 255) / 256, 256, 0, stream>>>(f2, wpf2, 128, 128, nf);
    }

    // conv1: 128 -> 64, relu  (4 waves: 2m x 2n, 96 px/block -> 1536 blocks)
    conv3x3_direct<128, 64, 2, 2, 2, 3, true, false>
        <<<dim3(2, HH, BB), 256, 0, stream>>>(xpad, wp1, b1, t1);
    // conv2: 64 -> 32, relu   (4 waves: 1m x 4n, 192 px/block -> 768 blocks)
    conv3x3_direct<64, 32, 1, 4, 2, 3, true, false>
        <<<dim3(1, HH, BB), 256, 0, stream>>>(t1, wp2, b2, t2);
    // conv3 1x1 + softmax -> kern
    conv1x1_softmax_kernel<<<(NPIX + 255) / 256, 256, 0, stream>>>(t2, w3, b3, kern);
    // adaptive filter apply (exact fp32 x) -> bf16 t3
    {
        int nd = BB * 16 * HWSZ;
        deblur_kernel<<<(nd + 255) / 256, 256, 0, stream>>>(x, kern, t3);
    }
    // f1: 128 -> 128, relu    (4 waves: 2m x 2n, WM=4, 96 px/block -> 1536 blocks)
    conv3x3_direct<128, 128, 2, 2, 4, 3, true, false>
        <<<dim3(2, HH, BB), 256, 0, stream>>>(t3, wpf1, fb1, t4);
    // f2: 128 -> 128, no relu -> final fp32 output
    conv3x3_direct<128, 128, 2, 2, 4, 3, false, true>
        <<<dim3(2, HH, BB), 256, 0, stream>>>(t4, wpf2, fb2, out);
}

// Round 5
// 429.715 us; speedup vs baseline: 4.9866x; 1.0027x over previous
//
#include <hip/hip_runtime.h>
#include <math.h>

// Problem constants (B, C, H, W) = (4, 128, 192, 192)
#define BB 4
#define CC 128
#define HH 192
#define WW 192
#define HWSZ (HH * WW)          // 36864
#define NPIX (BB * HWSZ)        // 147456
#define PD 194                  // padded H/W for bf16 activation buffers

typedef __attribute__((ext_vector_type(8))) short short8;
typedef __attribute__((ext_vector_type(4))) short short4v;
typedef __attribute__((ext_vector_type(4))) float float4v;

// fp32 -> bf16, round-to-nearest-even
__device__ __forceinline__ short f2bf(float f) {
    unsigned u = __float_as_uint(f);
    u += 0x7FFF + ((u >> 16) & 1);
    return (short)(u >> 16);
}
__device__ __forceinline__ float bf2f(short s) {
    return __uint_as_float(((unsigned)(unsigned short)s) << 16);
}

// ---------------------------------------------------------------------------
// Weight prep:  w[co][cin][ky][kx] fp32  ->  wp[ck][tap][co][ci] bf16
// (per-ck chunk contiguous -> LDS staging is a pure width-16 DMA)
// ---------------------------------------------------------------------------
__global__ void prep_w_kernel(const float* __restrict__ w,
                              short* __restrict__ wp,
                              int CIN, int COUT, int total) {
    int idx = blockIdx.x * blockDim.x + threadIdx.x;
    if (idx >= total) return;
    int ci  = idx & 31;
    int rem = idx >> 5;
    int co  = rem % COUT;
    int r2  = rem / COUT;
    int tap = r2 % 9;
    int ck  = r2 / 9;
    int cin = ck * 32 + ci;
    wp[idx] = f2bf(w[(co * CIN + cin) * 9 + tap]);
}

// ---------------------------------------------------------------------------
// Zero the borders of the three padded bf16 activation buffers.
// ---------------------------------------------------------------------------
__global__ void zero_pads_kernel(short* __restrict__ p0,
                                 short* __restrict__ p1,
                                 short* __restrict__ p2) {
    int idx = blockIdx.x * blockDim.x + threadIdx.x;
    if (idx >= 3 * 64 * 772) return;
    int e   = idx % 772;
    int bc  = (idx / 772) % 64;
    int buf = idx / (772 * 64);
    short* base = (buf == 0) ? p0 : (buf == 1) ? p1 : p2;
    int row, col;
    if (e < 194)      { row = 0;   col = e; }
    else if (e < 388) { row = 193; col = e - 194; }
    else { int e2 = e - 388; row = 1 + (e2 >> 1); col = (e2 & 1) * 193; }
    short8 z = {0, 0, 0, 0, 0, 0, 0, 0};
    *(short8*)&base[(((size_t)bc * PD + row) * PD + col) * 8] = z;
}

// ---------------------------------------------------------------------------
// x fp32 NCHW -> padded bf16 8c-blocked [b][cg][h+1][w+1][8]
// ---------------------------------------------------------------------------
__global__ void x_prep_kernel(const float* __restrict__ x,
                              short* __restrict__ xp) {
    int idx = blockIdx.x * blockDim.x + threadIdx.x;
    if (idx >= BB * 16 * HWSZ) return;
    int w  = idx % WW;
    int h  = (idx / WW) % HH;
    int cg = (idx / HWSZ) % 16;
    int b  = idx / (HWSZ * 16);
    const float* p = x + ((size_t)(b * CC + cg * 8) * HH + h) * WW + w;
    short8 pk;
#pragma unroll
    for (int j = 0; j < 8; ++j) pk[j] = f2bf(p[(size_t)j * HWSZ]);
    *(short8*)&xp[((((size_t)b * 16 + cg) * PD + h + 1) * PD + (w + 1)) * 8] = pk;
}

// ---------------------------------------------------------------------------
// Implicit-GEMM 3x3 conv, bf16 MFMA 16x16x32, fp32 accumulate.
// A (weights): staged into LDS once per CKS ck-chunks via global_load_lds,
//   then read as conflict-free contiguous ds_read_b128 per tap.
// B (activations): read directly from padded 8c-blocked bf16 global buffer
//   (L1/L2), ping-pong prefetched one K-step ahead; no barrier coupling.
// ---------------------------------------------------------------------------
template <int CIN, int COUT, int WAVES_M, int WAVES_N, int WM, int WN, int CKS,
          bool RELU, bool OUT_F32>
__global__ __launch_bounds__(WAVES_M * WAVES_N * 64, 4)
void conv3x3_wlds(const short* __restrict__ in,
                  const short* __restrict__ wp,   // [ck][tap][co][32ci] bf16
                  const float* __restrict__ bias,
                  void* __restrict__ outv) {
    constexpr int CKN   = CIN / 32;
    constexpr int CG_IN = CIN / 8;
    constexpr int CGO   = COUT / 8;
    constexpr int NT    = WAVES_M * WAVES_N * 64;
    constexpr int CHUNK = CKS * 9 * COUT * 32;       // shorts per stage
    static_assert(WAVES_M * WM * 16 == COUT, "M tiling");
    static_assert(WAVES_N * WN * 16 == 192, "N tiling");
    static_assert(CKN % CKS == 0, "CKS divides CKN");

    __shared__ __align__(16) short s_w[CHUNK];

    const int tid  = threadIdx.x;
    const int h    = blockIdx.x;
    const int b    = blockIdx.y;
    const int lane = tid & 63;
    const int wv   = tid >> 6;
    const int wv_m = wv % WAVES_M;
    const int wv_n = wv / WAVES_M;
    const int ln15 = lane & 15;
    const int lg   = lane >> 4;              // k-subgroup 0..3 (8 cins each)

    float4v acc[WM][WN];
#pragma unroll
    for (int mi = 0; mi < WM; ++mi)
#pragma unroll
        for (int ni = 0; ni < WN; ++ni)
            acc[mi][ni] = (float4v){0.f, 0.f, 0.f, 0.f};

    short8 Aa[2][WM], Bb[2][WN];

    // A from LDS: ckl = ck within current stage
    auto loadA = [&](int ckl, int tap, short8* dst) {
#pragma unroll
        for (int mi = 0; mi < WM; ++mi) {
            int co = (wv_m * WM + mi) * 16 + ln15;
            dst[mi] = *(const short8*)
                &s_w[(((ckl * 9 + tap) * COUT) + co) * 32 + lg * 8];
        }
    };
    // B from global (padded 8c-blocked)
    auto loadB = [&](int kt, short8* dst) {
        const int ck = kt / 9, tap = kt % 9;
        const int dy = tap / 3, dx = tap % 3;
#pragma unroll
        for (int ni = 0; ni < WN; ++ni) {
            int col = (wv_n * WN + ni) * 16 + ln15 + dx;
            dst[ni] = *(const short8*)
                &in[((((size_t)b * CG_IN + ck * 4 + lg) * PD + (h + dy)) * PD + col) * 8];
        }
    };

    loadB(0, Bb[0]);

    for (int cs = 0; cs < CKN / CKS; ++cs) {
        // ---- stage weight chunk into LDS (pure DMA) ----
        if (cs > 0) __syncthreads();         // prior-tap A reads done
        {
            const short* src = wp + (size_t)cs * CHUNK;
            constexpr int UNITS = CHUNK / 8;            // 16B units
#pragma unroll
            for (int u = 0; u < (UNITS + NT - 1) / NT; ++u) {
                int i = tid + u * NT;
                if (UNITS % NT == 0 || i < UNITS)
                    __builtin_amdgcn_global_load_lds(
                        (const __attribute__((address_space(1))) void*)&src[i * 8],
                        (__attribute__((address_space(3))) void*)&s_w[i * 8], 16, 0, 0);
            }
        }
        __syncthreads();                     // DMA drained (compiler vmcnt(0))

#pragma unroll
        for (int ckl = 0; ckl < CKS; ++ckl) {
            const int kt0 = (cs * CKS + ckl) * 9;
            loadA(ckl, 0, Aa[0]);
#pragma unroll
            for (int tap = 0; tap < 9; ++tap) {
                const int kt = kt0 + tap;
                if (tap < 8) loadA(ckl, tap + 1, Aa[(tap + 1) & 1]);
                if (kt + 1 < CKN * 9) loadB(kt + 1, Bb[(kt + 1) & 1]);
#pragma unroll
                for (int mi = 0; mi < WM; ++mi)
#pragma unroll
                    for (int ni = 0; ni < WN; ++ni)
                        acc[mi][ni] = __builtin_amdgcn_mfma_f32_16x16x32_bf16(
                            Aa[tap & 1][mi], Bb[kt & 1][ni], acc[mi][ni], 0, 0, 0);
            }
        }
    }

    // ---- epilogue: C layout col=lane&15 (pixel), row=lg*4+reg (cout) ----
    if (OUT_F32) {
        float* out = (float*)outv;
#pragma unroll
        for (int mi = 0; mi < WM; ++mi) {
            int co0 = (wv_m * WM + mi) * 16 + lg * 4;
#pragma unroll
            for (int r = 0; r < 4; ++r) {
                int co = co0 + r;
                float bv = bias[co];
#pragma unroll
                for (int ni = 0; ni < WN; ++ni) {
                    int wcol = (wv_n * WN + ni) * 16 + ln15;
                    float v = acc[mi][ni][r] + bv;
                    if (RELU) v = fmaxf(v, 0.f);
                    out[((size_t)(b * COUT + co) * HH + h) * WW + wcol] = v;
                }
            }
        }
    } else {
        short* out = (short*)outv;
#pragma unroll
        for (int mi = 0; mi < WM; ++mi) {
            int co0 = (wv_m * WM + mi) * 16 + lg * 4;    // 4 consecutive couts
            int cg  = co0 >> 3;
            int sub = co0 & 7;                           // 0 or 4
#pragma unroll
            for (int ni = 0; ni < WN; ++ni) {
                int wcol = (wv_n * WN + ni) * 16 + ln15;
                short4v pk;
#pragma unroll
                for (int r = 0; r < 4; ++r) {
                    float v = acc[mi][ni][r] + bias[co0 + r];
                    if (RELU) v = fmaxf(v, 0.f);
                    pk[r] = f2bf(v);
                }
                *(short4v*)&out[((((size_t)b * CGO + cg) * PD + (h + 1)) * PD +
                                 (wcol + 1)) * 8 + sub] = pk;
            }
        }
    }
}

// ---------------------------------------------------------------------------
// conv1x1 (32 -> 9 logits) + softmax; reads bf16 8c-blocked padded t2.
// ---------------------------------------------------------------------------
__global__ void conv1x1_softmax_kernel(const short* __restrict__ t2,
                                       const float* __restrict__ w3,   // (9,32)
                                       const float* __restrict__ b3,
                                       float* __restrict__ kern) {     // (B,9,H,W)
    __shared__ float sw[9 * 32];
    __shared__ float sb[9];
    for (int i = threadIdx.x; i < 9 * 32; i += blockDim.x) sw[i] = w3[i];
    if (threadIdx.x < 9) sb[threadIdx.x] = b3[threadIdx.x];
    __syncthreads();

    int idx = blockIdx.x * blockDim.x + threadIdx.x;
    if (idx >= NPIX) return;
    int b = idx / HWSZ;
    int p = idx % HWSZ;
    int h = p / WW, w = p % WW;

    float v[32];
#pragma unroll
    for (int cg = 0; cg < 4; ++cg) {
        short8 pk = *(const short8*)
            &t2[((((size_t)b * 4 + cg) * PD + h + 1) * PD + (w + 1)) * 8];
#pragma unroll
        for (int j = 0; j < 8; ++j) v[cg * 8 + j] = bf2f(pk[j]);
    }

    float lg[9];
    float m = -1e30f;
#pragma unroll
    for (int t = 0; t < 9; ++t) {
        float s = sb[t];
#pragma unroll
        for (int c = 0; c < 32; ++c) s = fmaf(sw[t * 32 + c], v[c], s);
        lg[t] = s;
        m = fmaxf(m, s);
    }
    float sum = 0.f;
#pragma unroll
    for (int t = 0; t < 9; ++t) {
        lg[t] = __expf(lg[t] - m);
        sum += lg[t];
    }
    float inv = 1.f / sum;
#pragma unroll
    for (int t = 0; t < 9; ++t)
        kern[((size_t)(b * 9 + t)) * HWSZ + p] = lg[t] * inv;
}

// ---------------------------------------------------------------------------
// Adaptive 3x3 filter apply: fp32 x (exact) * fp32 kernel -> bf16 8c t3.
// ---------------------------------------------------------------------------
__global__ void deblur_kernel(const float* __restrict__ x,
                              const float* __restrict__ kern,
                              short* __restrict__ t3) {
    int idx = blockIdx.x * blockDim.x + threadIdx.x;
    if (idx >= BB * 16 * HWSZ) return;
    int w  = idx % WW;
    int h  = (idx / WW) % HH;
    int cg = (idx / HWSZ) % 16;
    int b  = idx / (HWSZ * 16);

    const float* kb = kern + (size_t)(b * 9) * HWSZ + h * WW + w;
    float kv[9];
#pragma unroll
    for (int t = 0; t < 9; ++t) kv[t] = kb[(size_t)t * HWSZ];

    const float* xb = x + (size_t)(b * CC + cg * 8) * HWSZ;
    float s[8] = {0.f, 0.f, 0.f, 0.f, 0.f, 0.f, 0.f, 0.f};
    int t = 0;
#pragma unroll
    for (int dy = 0; dy < 3; ++dy) {
#pragma unroll
        for (int dx = 0; dx < 3; ++dx) {
            int hh = h + dy - 1, ww2 = w + dx - 1;
            if ((unsigned)hh < (unsigned)HH && (unsigned)ww2 < (unsigned)WW) {
                const float* xp = xb + hh * WW + ww2;
#pragma unroll
                for (int j = 0; j < 8; ++j)
                    s[j] = fmaf(kv[t], xp[(size_t)j * HWSZ], s[j]);
            }
            ++t;
        }
    }
    short8 pk;
#pragma unroll
    for (int j = 0; j < 8; ++j) pk[j] = f2bf(s[j]);
    *(short8*)&t3[((((size_t)b * 16 + cg) * PD + h + 1) * PD + (w + 1)) * 8] = pk;
}

// ---------------------------------------------------------------------------
extern "C" void kernel_launch(void* const* d_in, const int* in_sizes, int n_in,
                              void* d_out, int out_size, void* d_ws, size_t ws_size,
                              hipStream_t stream) {
    const float* x   = (const float*)d_in[0];
    const float* w1  = (const float*)d_in[1];
    const float* b1  = (const float*)d_in[2];
    const float* w2  = (const float*)d_in[3];
    const float* b2  = (const float*)d_in[4];
    const float* w3  = (const float*)d_in[5];
    const float* b3  = (const float*)d_in[6];
    const float* f1  = (const float*)d_in[7];
    const float* fb1 = (const float*)d_in[8];
    const float* f2  = (const float*)d_in[9];
    const float* fb2 = (const float*)d_in[10];
    float* out = (float*)d_out;

    // workspace layout (bf16 activation buffers are padded 8c-blocked)
    const size_t ACT_SZ = (size_t)BB * 16 * PD * PD * 8;   // shorts, 128ch buffer
    short* xpad    = (short*)d_ws;
    short* regionA = xpad + ACT_SZ;       // t1 (64ch) then t3 (128ch)
    short* regionB = regionA + ACT_SZ;    // t2 (32ch) then t4 (128ch)
    float* kern    = (float*)(regionB + ACT_SZ);           // (B,9,H,W) fp32
    short* wp1     = (short*)(kern + (size_t)BB * 9 * HWSZ);
    short* wp2     = wp1 + 9 * 4 * 64 * 32;
    short* wpf1    = wp2 + 9 * 2 * 32 * 32;
    short* wpf2    = wpf1 + 9 * 4 * 128 * 32;

    short* t1 = regionA;
    short* t2 = regionB;
    short* t3 = regionA;   // overwrites t1 (dead)
    short* t4 = regionB;   // overwrites t2 (dead)

    // border zeroing + x conversion + weight prep
    {
        int nz = 3 * 64 * 772;
        zero_pads_kernel<<<(nz + 255) / 256, 256, 0, stream>>>(xpad, regionA, regionB);
        int nx = BB * 16 * HWSZ;
        x_prep_kernel<<<(nx + 255) / 256, 256, 0, stream>>>(x, xpad);
        int n1 = 9 * 4 * 64 * 32, n2 = 9 * 2 * 32 * 32, nf = 9 * 4 * 128 * 32;
        prep_w_kernel<<<(n1 + 255) / 256, 256, 0, stream>>>(w1, wp1, 128, 64, n1);
        prep_w_kernel<<<(n2 + 255) / 256, 256, 0, stream>>>(w2, wp2, 64, 32, n2);
        prep_w_kernel<<<(nf + 255) / 256, 256, 0, stream>>>(f1, wpf1, 128, 128, nf);
        prep_w_kernel<<<(nf + 255) / 256, 256, 0, stream>>>(f2, wpf2, 128, 128, nf);
    }

    // conv1: 128 -> 64, relu. 4 waves (1m x 4n), WM=4 (no B dup), per-ck LDS 36.9 KB
    conv3x3_wlds<128, 64, 1, 4, 4, 3, 1, true, false>
        <<<dim3(HH, BB), 256, 0, stream>>>(xpad, wp1, b1, t1);
    // conv2: 64 -> 32, relu. 4 waves (1m x 4n), WM=2, whole weight set staged once
    conv3x3_wlds<64, 32, 1, 4, 2, 3, 2, true, false>
        <<<dim3(HH, BB), 256, 0, stream>>>(t1, wp2, b2, t2);
    // conv3 1x1 + softmax -> kern
    conv1x1_softmax_kernel<<<(NPIX + 255) / 256, 256, 0, stream>>>(t2, w3, b3, kern);
    // adaptive filter apply (exact fp32 x) -> bf16 t3
    {
        int nd = BB * 16 * HWSZ;
        deblur_kernel<<<(nd + 255) / 256, 256, 0, stream>>>(x, kern, t3);
    }
    // f1: 128 -> 128, relu. 8 waves (2m x 4n), WM=4, per-ck LDS 73.7 KB
    conv3x3_wlds<128, 128, 2, 4, 4, 3, 1, true, false>
        <<<dim3(HH, BB), 512, 0, stream>>>(t3, wpf1, fb1, t4);
    // f2: 128 -> 128, no relu -> final fp32 output
    conv3x3_wlds<128, 128, 2, 4, 4, 3, 1, false, true>
        <<<dim3(HH, BB), 512, 0, stream>>>(t4, wpf2, fb2, out);
}